// Round 3
// baseline (70.794 us; speedup 1.0000x reference)
//
#include <hip/hip_runtime.h>

// FractalEmbedding: out[b,l,d] = scale * sum_f feats(token)[f] * W[d,f]
// feats = 8-step Julia iteration on c_table[token], interleaved (zr,zi).
//
// B=8, L=8192 -> 65536 tokens; D=1024; 16 features. Output 268 MB f32.
// Write-BW bound: fill kernel sustains 7.0 TB/s (plain stores). R1 measured
// 57.9us = VALU-issue + store-drain fully SERIALIZED (53K + 92K cy/SIMD).
// This version targets overlap:
//  - 2 dims/thread (w = 32 VGPR), BLOCK=512, __launch_bounds__(512,8)
//    -> <=64 VGPR -> 8 waves/SIMD (was ~100 VGPR -> 4 waves/SIMD)
//  - plain (not nontemporal) stores: the 7 TB/s fill evidence is plain;
//    NT bypassing L2 is the prime suspect for R1's 4.6 TB/s effective BW
//  - keeps R1's fused dot + 2-token ILP + scalar prefetch of tok/ctab
//  - GRID=1024 = exact residency (4 blocks/CU), no tail imbalance

#define STEPS 8
#define NFEAT (2 * STEPS)
#define EMBED 1024
#define NTOK (8 * 8192)
#define NPAIR (NTOK / 2)
#define BLOCK 512
#define GRID 1024

__global__ __launch_bounds__(BLOCK, 8) void FractalEmbedding_30365418782757_kernel(
    const int* __restrict__ tok,
    const float* __restrict__ ctab,   // (V, 2)
    const float* __restrict__ W,      // (1024, 16) row-major
    const float* __restrict__ scale_p,
    float* __restrict__ out)          // (NTOK, 1024)
{
    const int t = threadIdx.x;  // thread t -> output dims 2t, 2t+1
    const float s = *scale_p;

    // This thread's 2 W rows in registers, scale pre-folded (32 VGPRs).
    float w0[NFEAT], w1[NFEAT];
    {
        const float4* r0 = reinterpret_cast<const float4*>(W + (size_t)(2 * t) * NFEAT);
        const float4* r1 = reinterpret_cast<const float4*>(W + (size_t)(2 * t + 1) * NFEAT);
#pragma unroll
        for (int q = 0; q < 4; ++q) {
            float4 a = r0[q];
            w0[4 * q + 0] = a.x * s; w0[4 * q + 1] = a.y * s;
            w0[4 * q + 2] = a.z * s; w0[4 * q + 3] = a.w * s;
            float4 b = r1[q];
            w1[4 * q + 0] = b.x * s; w1[4 * q + 1] = b.y * s;
            w1[4 * q + 2] = b.z * s; w1[4 * q + 3] = b.w * s;
        }
    }

    const int2*   tok2  = reinterpret_cast<const int2*>(tok);
    const float2* ctab2 = reinterpret_cast<const float2*>(ctab);
    float2* out2 = reinterpret_cast<float2*>(out);

    // Prologue: first pair's ids + constants (wave-uniform scalar loads).
    int p = blockIdx.x;
    int2   id = tok2[p];
    float2 c0 = ctab2[id.x];
    float2 c1 = ctab2[id.y];

    for (; p < NPAIR; p += GRID) {
        // Prefetch next pair (clamped in-bounds); overlaps the dependent
        // tok->ctab scalar chain with this pair's compute.
        const int pn = p + GRID;
        const int pc = (pn < NPAIR) ? pn : p;
        int2   idn = tok2[pc];
        float2 cn0 = ctab2[idn.x];
        float2 cn1 = ctab2[idn.y];

        // Two interleaved Julia recurrences, dot fused per step.
        // Accumulation order per output dim matches the reference
        // (f0*w0, f1*w1, ... sequentially).
        float a00 = 0.f, a01 = 0.f;   // token0: dims 2t, 2t+1
        float a10 = 0.f, a11 = 0.f;   // token1: dims 2t, 2t+1
        float zr0 = 0.f, zi0 = 0.f, zr1 = 0.f, zi1 = 0.f;
#pragma unroll
        for (int st = 0; st < STEPS; ++st) {
            float x0 = zr0 * zr0 - zi0 * zi0 + c0.x;
            float y0 = 2.0f * zr0 * zi0 + c0.y;
            zr0 = x0; zi0 = y0;
            float x1 = zr1 * zr1 - zi1 * zi1 + c1.x;
            float y1 = 2.0f * zr1 * zi1 + c1.y;
            zr1 = x1; zi1 = y1;
            a00 += zr0 * w0[2 * st]; a00 += zi0 * w0[2 * st + 1];
            a01 += zr0 * w1[2 * st]; a01 += zi0 * w1[2 * st + 1];
            a10 += zr1 * w0[2 * st]; a10 += zi1 * w0[2 * st + 1];
            a11 += zr1 * w1[2 * st]; a11 += zi1 * w1[2 * st + 1];
        }

        float2 o0; o0.x = a00; o0.y = a01;
        float2 o1; o1.x = a10; o1.y = a11;
        out2[(size_t)(2 * p)     * (EMBED / 2) + t] = o0;  // coalesced dwordx2
        out2[(size_t)(2 * p + 1) * (EMBED / 2) + t] = o1;

        c0 = cn0;
        c1 = cn1;
    }
}

extern "C" void kernel_launch(void* const* d_in, const int* in_sizes, int n_in,
                              void* d_out, int out_size, void* d_ws, size_t ws_size,
                              hipStream_t stream) {
    const int*   tok   = (const int*)d_in[0];
    const float* ctab  = (const float*)d_in[1];
    const float* W     = (const float*)d_in[2];
    const float* scale = (const float*)d_in[3];
    float*       out   = (float*)d_out;

    FractalEmbedding_30365418782757_kernel<<<GRID, BLOCK, 0, stream>>>(tok, ctab, W, scale, out);
}

// Round 4
// 55.255 us; speedup vs baseline: 1.2812x; 1.2812x over previous
//
#include <hip/hip_runtime.h>

// FractalEmbedding: out[b,l,d] = scale * sum_f feats(token)[f] * W[d,f]
// feats = 8-step Julia iteration on c_table[token], interleaved (zr,zi).
//
// B=8, L=8192 -> 65536 tokens; D=1024; 16 features. Output 268 MB f32.
// Write-BW bound: fill kernel sustains 7.0 TB/s. R2/R3 fit an ADDITIVE
// VALU+store model => the per-iteration tok/ctab load waits serialize the
// loop against its own store stream (vmcnt(0) drain or s_load chain stall).
// This version decouples them:
//  - block owns 64 consecutive tokens; wave 0 gathers their c-values into
//    LDS once (one barrier); main loop has ZERO vmem loads -> no vmcnt
//    waits until endpgm, stores stream freely (16 iters x 2 stores << 63)
//  - c read from LDS broadcast (lgkmcnt, prefetched one iteration ahead)
//  - 4 dims/thread (R2 geometry, lowest proven VALU cost), fused dot
//  - plain float4 stores (fill evidence: plain stores reach 7 TB/s)
//  - GRID=1024, BLOCK=256: exact residency, no tail

#define STEPS 8
#define NFEAT (2 * STEPS)
#define EMBED 1024
#define NTOK (8 * 8192)
#define TPB 64                 // tokens per block
#define BLOCK 256
#define GRID (NTOK / TPB)      // 1024

__global__ __launch_bounds__(BLOCK, 4) void FractalEmbedding_30365418782757_kernel(
    const int* __restrict__ tok,
    const float* __restrict__ ctab,   // (V, 2)
    const float* __restrict__ W,      // (1024, 16) row-major
    const float* __restrict__ scale_p,
    float* __restrict__ out)          // (NTOK, 1024)
{
    const int t = threadIdx.x;  // thread t -> output dims 4t .. 4t+3
    const float s = *scale_p;

    __shared__ float2 cs[TPB];

    const int base = blockIdx.x * TPB;
    if (t < TPB) {
        const int id = tok[base + t];                       // coalesced 256B
        cs[t] = reinterpret_cast<const float2*>(ctab)[id];  // one-time gather
    }

    // This thread's 4 W rows in registers, scale pre-folded (64 VGPRs).
    float w[4][NFEAT];
#pragma unroll
    for (int r = 0; r < 4; ++r) {
        const float4* wrow = reinterpret_cast<const float4*>(W + (size_t)(4 * t + r) * NFEAT);
#pragma unroll
        for (int q = 0; q < 4; ++q) {
            float4 v = wrow[q];
            w[r][4 * q + 0] = v.x * s;
            w[r][4 * q + 1] = v.y * s;
            w[r][4 * q + 2] = v.z * s;
            w[r][4 * q + 3] = v.w * s;
        }
    }

    __syncthreads();

    // Main loop: pure VALU + LDS broadcast + stores. No global loads.
    float2 c0 = cs[0];
    float2 c1 = cs[1];
#pragma unroll 1
    for (int i = 0; i < TPB; i += 2) {
        // Prefetch next pair's c from LDS (broadcast, conflict-free).
        const int nn = (i + 2 < TPB) ? (i + 2) : i;
        float2 cn0 = cs[nn];
        float2 cn1 = cs[nn + 1];

        // Two interleaved Julia recurrences, dot fused per step.
        // Accumulation order per output dim matches the reference
        // (f0*w0, f1*w1, ... sequentially).
        float acc0[4] = {0.f, 0.f, 0.f, 0.f};
        float acc1[4] = {0.f, 0.f, 0.f, 0.f};
        float zr0 = 0.f, zi0 = 0.f, zr1 = 0.f, zi1 = 0.f;
#pragma unroll
        for (int st = 0; st < STEPS; ++st) {
            float x0 = zr0 * zr0 - zi0 * zi0 + c0.x;
            float y0 = 2.0f * zr0 * zi0 + c0.y;
            zr0 = x0; zi0 = y0;
            float x1 = zr1 * zr1 - zi1 * zi1 + c1.x;
            float y1 = 2.0f * zr1 * zi1 + c1.y;
            zr1 = x1; zi1 = y1;
#pragma unroll
            for (int r = 0; r < 4; ++r) {
                acc0[r] += zr0 * w[r][2 * st];
                acc0[r] += zi0 * w[r][2 * st + 1];
                acc1[r] += zr1 * w[r][2 * st];
                acc1[r] += zi1 * w[r][2 * st + 1];
            }
        }

        float4 o0; o0.x = acc0[0]; o0.y = acc0[1]; o0.z = acc0[2]; o0.w = acc0[3];
        float4 o1; o1.x = acc1[0]; o1.y = acc1[1]; o1.z = acc1[2]; o1.w = acc1[3];
        reinterpret_cast<float4*>(out + (size_t)(base + i)     * EMBED)[t] = o0;
        reinterpret_cast<float4*>(out + (size_t)(base + i + 1) * EMBED)[t] = o1;

        c0 = cn0;
        c1 = cn1;
    }
}

extern "C" void kernel_launch(void* const* d_in, const int* in_sizes, int n_in,
                              void* d_out, int out_size, void* d_ws, size_t ws_size,
                              hipStream_t stream) {
    const int*   tok   = (const int*)d_in[0];
    const float* ctab  = (const float*)d_in[1];
    const float* W     = (const float*)d_in[2];
    const float* scale = (const float*)d_in[3];
    float*       out   = (float*)d_out;

    FractalEmbedding_30365418782757_kernel<<<GRID, BLOCK, 0, stream>>>(tok, ctab, W, scale, out);
}

// Round 5
// 50.273 us; speedup vs baseline: 1.4082x; 1.0991x over previous
//
#include <hip/hip_runtime.h>

// FractalEmbedding: out[b,l,d] = scale * sum_f feats(token)[f] * W[d,f]
// feats = 8-step Julia iteration on c_table[token], interleaved (zr,zi).
//
// B=8, L=8192 -> 65536 tokens; D=1024; 16 features. Output 268 MB f32.
// Model from R2/R3/R4: dur ~= 38us store-drain + 0.76 * VALU-issue.
// Store path has headroom (fill: 7 TB/s); VALU count is the lever.
// This version cuts VALU issue ~2.4x:
//  - Julia dedup: threads 0..63 compute all 64 tokens' feats ONCE into
//    4 KB LDS (bit-identical); main loop reads them via broadcast
//    ds_read_b128 (same-address -> conflict-free) instead of every wave
//    recomputing the recurrence (was ~32 VALU/token/wave).
//  - packed-FP32 dot: accumulators packed across independent output dims
//    (floatx2 = dims {4t+2j, 4t+2j+1}) -> v_pk_fma_f32; each dim's
//    accumulation order stays exactly f0*w0, f1*w1, ... (reference order).
//  - zero global loads in main loop (R4 property kept); plain float4 stores.
//  - GRID=1024, BLOCK=256, 4 dims/thread: exact residency, no tail.

#define STEPS 8
#define NFEAT (2 * STEPS)
#define EMBED 1024
#define NTOK (8 * 8192)
#define TPB 64                 // tokens per block
#define BLOCK 256
#define GRID (NTOK / TPB)      // 1024

typedef float floatx2 __attribute__((ext_vector_type(2)));

__global__ __launch_bounds__(BLOCK, 4) void FractalEmbedding_30365418782757_kernel(
    const int* __restrict__ tok,
    const float* __restrict__ ctab,   // (V, 2)
    const float* __restrict__ W,      // (1024, 16) row-major
    const float* __restrict__ scale_p,
    float* __restrict__ out)          // (NTOK, 1024)
{
    const int t = threadIdx.x;  // thread t -> output dims 4t .. 4t+3
    const float s = *scale_p;

    __shared__ float fs[TPB][NFEAT];   // 4 KB: per-token features

    const int base = blockIdx.x * TPB;

    // One-time: threads 0..63 compute one token's Julia features each.
    if (t < TPB) {
        const int id = tok[base + t];
        const float2 c = reinterpret_cast<const float2*>(ctab)[id];
        float loc[NFEAT];
        float zr = 0.0f, zi = 0.0f;
#pragma unroll
        for (int st = 0; st < STEPS; ++st) {
            float nzr = zr * zr - zi * zi + c.x;
            float nzi = 2.0f * zr * zi + c.y;
            zr = nzr; zi = nzi;
            loc[2 * st]     = zr;
            loc[2 * st + 1] = zi;
        }
        float4* dst = reinterpret_cast<float4*>(fs[t]);
#pragma unroll
        for (int q = 0; q < 4; ++q)
            dst[q] = reinterpret_cast<const float4*>(loc)[q];
    }

    // W packed across dim-pairs: wp[j][k] = { W[4t+2j][k], W[4t+2j+1][k] } * s
    floatx2 wp[2][NFEAT];
#pragma unroll
    for (int j = 0; j < 2; ++j) {
        const float4* r0 = reinterpret_cast<const float4*>(W + (size_t)(4 * t + 2 * j)     * NFEAT);
        const float4* r1 = reinterpret_cast<const float4*>(W + (size_t)(4 * t + 2 * j + 1) * NFEAT);
#pragma unroll
        for (int q = 0; q < 4; ++q) {
            float4 a = r0[q];
            float4 b = r1[q];
            wp[j][4 * q + 0] = floatx2{a.x * s, b.x * s};
            wp[j][4 * q + 1] = floatx2{a.y * s, b.y * s};
            wp[j][4 * q + 2] = floatx2{a.z * s, b.z * s};
            wp[j][4 * q + 3] = floatx2{a.w * s, b.w * s};
        }
    }

    __syncthreads();

    // Main loop: LDS broadcast reads + packed FMA + stores. No global loads.
#pragma unroll 1
    for (int i = 0; i < TPB; i += 2) {
        // Both tokens' 16 feats via broadcast ds_read_b128 (conflict-free).
        float g0[NFEAT], g1[NFEAT];
        const float4* p0 = reinterpret_cast<const float4*>(fs[i]);
        const float4* p1 = reinterpret_cast<const float4*>(fs[i + 1]);
#pragma unroll
        for (int q = 0; q < 4; ++q) {
            float4 v0 = p0[q];
            g0[4 * q + 0] = v0.x; g0[4 * q + 1] = v0.y;
            g0[4 * q + 2] = v0.z; g0[4 * q + 3] = v0.w;
            float4 v1 = p1[q];
            g1[4 * q + 0] = v1.x; g1[4 * q + 1] = v1.y;
            g1[4 * q + 2] = v1.z; g1[4 * q + 3] = v1.w;
        }

        // Packed dot: per-dim chain order is exactly k = 0..15 (reference).
        floatx2 a00 = {0.f, 0.f}, a01 = {0.f, 0.f};   // token0 dims {0,1},{2,3}
        floatx2 a10 = {0.f, 0.f}, a11 = {0.f, 0.f};   // token1
#pragma unroll
        for (int k = 0; k < NFEAT; ++k) {
            floatx2 fb0 = {g0[k], g0[k]};
            floatx2 fb1 = {g1[k], g1[k]};
            a00 += fb0 * wp[0][k];
            a01 += fb0 * wp[1][k];
            a10 += fb1 * wp[0][k];
            a11 += fb1 * wp[1][k];
        }

        float4 o0; o0.x = a00.x; o0.y = a00.y; o0.z = a01.x; o0.w = a01.y;
        float4 o1; o1.x = a10.x; o1.y = a10.y; o1.z = a11.x; o1.w = a11.y;
        reinterpret_cast<float4*>(out + (size_t)(base + i)     * EMBED)[t] = o0;
        reinterpret_cast<float4*>(out + (size_t)(base + i + 1) * EMBED)[t] = o1;
    }
}

extern "C" void kernel_launch(void* const* d_in, const int* in_sizes, int n_in,
                              void* d_out, int out_size, void* d_ws, size_t ws_size,
                              hipStream_t stream) {
    const int*   tok   = (const int*)d_in[0];
    const float* ctab  = (const float*)d_in[1];
    const float* W     = (const float*)d_in[2];
    const float* scale = (const float*)d_in[3];
    float*       out   = (float*)d_out;

    FractalEmbedding_30365418782757_kernel<<<GRID, BLOCK, 0, stream>>>(tok, ctab, W, scale, out);
}